// Round 14
// baseline (1262.842 us; speedup 1.0000x reference)
//
#include <hip/hip_runtime.h>

#define HID   24
#define T_LEN 4096
#define BATCH 1024
#define NB    2                  // batches per block (one per 32-lane half)
#define K     16                 // timesteps per chunk
#define NC    (T_LEN / K)        // 256 chunks
#define CTOT  (NC + 1)           // 257 ticks (wave1 lags one chunk)
#define TPB   128                // wave0 = layer0; wave1 = layers 1+2 fused
#define RSTR  32                 // padded pub row stride (f16 elems)

typedef __attribute__((ext_vector_type(2))) _Float16 h2v;
typedef __attribute__((ext_vector_type(4))) int      int4v;
typedef __attribute__((ext_vector_type(2))) unsigned int uint2v;

#if __has_builtin(__builtin_amdgcn_fdot2)
__device__ __forceinline__ float dot2f(int p, int w, float acc) {
    return __builtin_amdgcn_fdot2(__builtin_bit_cast(h2v, p),
                                  __builtin_bit_cast(h2v, w), acc, false);
}
#else
__device__ __forceinline__ float dot2f(int p, int w, float acc) {
    h2v a = __builtin_bit_cast(h2v, p), b = __builtin_bit_cast(h2v, w);
    acc = fmaf((float)a.x, (float)b.x, acc);
    return fmaf((float)a.y, (float)b.y, acc);
}
#endif

__device__ __forceinline__ float dot4(const float4 a, const float4 b, float acc) {
    acc = fmaf(a.x, b.x, acc);
    acc = fmaf(a.y, b.y, acc);
    acc = fmaf(a.z, b.z, acc);
    return fmaf(a.w, b.w, acc);
}

template<int N> __device__ __forceinline__ int rr(int v) {
    return __builtin_amdgcn_mov_dpp(v, 0x120 + N, 0xF, 0xF, false);
}
__device__ __forceinline__ int qp_nbr(int v) {
    return __builtin_amdgcn_mov_dpp(v, 0xB1, 0xF, 0xF, false);
}

#define PKF(A_, B_)                                                                 \
    (((int)__builtin_bit_cast(unsigned short, (_Float16)(B_)) << 16) |              \
     (int)__builtin_bit_cast(unsigned short, (_Float16)(A_)))

// weight pair for pair index m, odd-lane half swap (validated r10/r11)
__device__ __forceinline__ int pkw(const float* row, int m, int par) {
    float wl = row[2 * m], wh = row[2 * m + 1];
    if (par) { float t = wl; wl = wh; wh = t; }
    return PKF(wl, wh);
}

// build 12 gather-order weight dwords for one 24-wide row (validated r10/r11)
__device__ __forceinline__ void build_g(const float* row, int lane, int dir,
                                        int par, int* g) {
    #pragma unroll
    for (int k = 0; k < 12; ++k) {
        const int r = (k < 8) ? (2 * k) : (2 * (k - 8));
        const int s = ((lane & 15) + dir * r) & 15;
        const int m = (k < 8) ? (s >> 1) : (8 + ((s >> 1) & 3));
        g[k] = pkw(row, m, par);
    }
}

template<bool USE_BP>
__device__ __forceinline__ void run_rnn(
    const float* __restrict__ x, const float* __restrict__ h_in,
    const float* __restrict__ Wih0, const float* __restrict__ bih0,
    const float* __restrict__ Whh0, const float* __restrict__ bhh0,
    const float* __restrict__ Wih1, const float* __restrict__ bih1,
    const float* __restrict__ Whh1, const float* __restrict__ bhh1,
    const float* __restrict__ Wih2, const float* __restrict__ bih2,
    const float* __restrict__ Whh2, const float* __restrict__ bhh2,
    const float* __restrict__ W1,   const float* __restrict__ b1,
    const float* __restrict__ W2,   const float* __restrict__ b2,
    float* __restrict__ out, const int dir, const bool flip,
    _Float16* pub, float (*h2f)[HID], float (*mbuf)[HID])
{
    const int tid  = threadIdx.x;
    const int w    = tid >> 6;        // 0: layer0 wave; 1: layers1+2 wave
    const int lane = tid & 63;
    const int bl   = lane >> 5;
    const int jj   = lane & 31;
    const bool act = (jj < HID);
    const int uL   = act ? jj : (jj - 8);
    const int par  = lane & 1;
    const int bg   = blockIdx.x * NB + bl;
    const int alo  = (((lane & 32) | (lane & 15)) << 2);
    const int ahi  = (((lane & 32) | 16 | (lane & 15)) << 2);

    // ---- weights ----
    int g0[12];                        // wave0: Whh0, gather order
    int g1h[12], g2i[12], g2h[12];     // wave1: Whh1 / Wih2 / Whh2, gather order
    int4v w1A = {0,0,0,0}, w1B = {0,0,0,0}, w1C = {0,0,0,0};  // Wih1, natural
    float wx0 = 0.f, bias0 = 0.f, bias1 = 0.f, bias2 = 0.f;
    if (w == 0) {
        build_g(Whh0 + uL * HID, lane, dir, par, g0);
        wx0 = Wih0[uL];
        bias0 = bih0[uL] + bhh0[uL];
    } else {
        build_g(Whh1 + uL * HID, lane, dir, par, g1h);
        build_g(Wih2 + uL * HID, lane, dir, par, g2i);
        build_g(Whh2 + uL * HID, lane, dir, par, g2h);
        const float* r_ = Wih1 + uL * HID;
        w1A = (int4v){PKF(r_[0], r_[1]),   PKF(r_[2], r_[3]),
                      PKF(r_[4], r_[5]),   PKF(r_[6], r_[7])};
        w1B = (int4v){PKF(r_[8], r_[9]),   PKF(r_[10], r_[11]),
                      PKF(r_[12], r_[13]), PKF(r_[14], r_[15])};
        w1C = (int4v){PKF(r_[16], r_[17]), PKF(r_[18], r_[19]),
                      PKF(r_[20], r_[21]), PKF(r_[22], r_[23])};
        bias1 = bih1[uL] + bhh1[uL];
        bias2 = bih2[uL] + bhh2[uL];
    }

    float cur0 = 0.f, cur1 = 0.f, cur2 = 0.f;
    if (w == 0) cur0 = h_in[(0 * BATCH + bg) * HID + uL];
    else {
        cur1 = h_in[(1 * BATCH + bg) * HID + uL];
        cur2 = h_in[(2 * BATCH + bg) * HID + uL];
    }

#define GATHER(CF_, R_) do {                                                        \
    int hc_ = (int)(unsigned)__builtin_bit_cast(unsigned short, (_Float16)(CF_));   \
    int pk_ = (qp_nbr(hc_) << 16) | hc_;                                            \
    int ea_, eb_;                                                                   \
    if constexpr (USE_BP) {                                                         \
        ea_ = __builtin_amdgcn_ds_bpermute(alo, pk_);                               \
        eb_ = __builtin_amdgcn_ds_bpermute(ahi, pk_);                               \
    } else {                                                                        \
        uint2v s_ = __builtin_amdgcn_permlane16_swap((unsigned)pk_, (unsigned)pk_,  \
                                                     false, false);                 \
        ea_ = flip ? (int)s_.y : (int)s_.x;                                         \
        eb_ = flip ? (int)s_.x : (int)s_.y;                                         \
    }                                                                               \
    R_[0] = ea_;         R_[1] = rr<2>(ea_);   R_[2] = rr<4>(ea_);                  \
    R_[3] = rr<6>(ea_);  R_[4] = rr<8>(ea_);   R_[5] = rr<10>(ea_);                 \
    R_[6] = rr<12>(ea_); R_[7] = rr<14>(ea_);                                       \
    R_[8] = eb_;         R_[9] = rr<2>(eb_);   R_[10] = rr<4>(eb_);                 \
    R_[11] = rr<6>(eb_);                                                            \
} while (0)

#define DOT12G(R_, W_, A0_, A1_)                                                    \
    A0_ = dot2f(R_[0], W_[0], A0_);   A1_ = dot2f(R_[1], W_[1], A1_);               \
    A0_ = dot2f(R_[2], W_[2], A0_);   A1_ = dot2f(R_[3], W_[3], A1_);               \
    A0_ = dot2f(R_[4], W_[4], A0_);   A1_ = dot2f(R_[5], W_[5], A1_);               \
    A0_ = dot2f(R_[6], W_[6], A0_);   A1_ = dot2f(R_[7], W_[7], A1_);               \
    A0_ = dot2f(R_[8], W_[8], A0_);   A1_ = dot2f(R_[9], W_[9], A1_);               \
    A0_ = dot2f(R_[10], W_[10], A0_); A1_ = dot2f(R_[11], W_[11], A1_);

#define DOT12N(V0_, V1_, V2_, A0_, A1_)                                             \
    A0_ = dot2f(V0_.x, w1A.x, A0_); A1_ = dot2f(V0_.y, w1A.y, A1_);                 \
    A0_ = dot2f(V0_.z, w1A.z, A0_); A1_ = dot2f(V0_.w, w1A.w, A1_);                 \
    A0_ = dot2f(V1_.x, w1B.x, A0_); A1_ = dot2f(V1_.y, w1B.y, A1_);                 \
    A0_ = dot2f(V1_.z, w1B.z, A0_); A1_ = dot2f(V1_.w, w1B.w, A1_);                 \
    A0_ = dot2f(V2_.x, w1C.x, A0_); A1_ = dot2f(V2_.y, w1C.y, A1_);                 \
    A0_ = dot2f(V2_.z, w1C.z, A0_); A1_ = dot2f(V2_.w, w1C.w, A1_);

    int R0v[12], R1v[12], R2v[12];
    if (w == 0) GATHER(cur0, R0v);
    else { GATHER(cur1, R1v); GATHER(cur2, R2v); }

    // x quads (wave0)
    const float* xrow = x + (size_t)bg * T_LEN;
    float4 xq0, xq1, xq2, xq3;
    xq0 = xq1 = xq2 = xq3 = make_float4(0.f, 0.f, 0.f, 0.f);
    if (w == 0) {
        const float4* xr = (const float4*)xrow;
        xq0 = xr[0]; xq1 = xr[1]; xq2 = xr[2]; xq3 = xr[3];
    }
#define XV(S)                                                                       \
    ((S) == 0 ? xq0.x : (S) == 1 ? xq0.y : (S) == 2 ? xq0.z : (S) == 3 ? xq0.w      \
   : (S) == 4 ? xq1.x : (S) == 5 ? xq1.y : (S) == 6 ? xq1.z : (S) == 7 ? xq1.w      \
   : (S) == 8 ? xq2.x : (S) == 9 ? xq2.y : (S) == 10 ? xq2.z : (S) == 11 ? xq2.w    \
   : (S) == 12 ? xq3.x : (S) == 13 ? xq3.y : (S) == 14 ? xq3.z : xq3.w)

    __syncthreads();

    // ---- ticks: wave0 computes chunk c (c<NC); wave1 consumes chunk c-1 (c>=1) ----
    for (int c = 0; c < CTOT; ++c) {
        const int wp = c & 1, rp = wp ^ 1;
        if (w == 0) {
            if (c < NC) {
                float4 xn0, xn1, xn2, xn3;
                const bool pf = (c + 1 < NC);
                if (pf) {
                    const float4* xn = (const float4*)(xrow + (size_t)(c + 1) * K);
                    xn0 = xn[0]; xn1 = xn[1]; xn2 = xn[2]; xn3 = xn[3];
                }
                _Float16* dst = pub + (size_t)(wp * NB + bl) * K * RSTR;
                #pragma unroll
                for (int s = 0; s < K; ++s) {
                    float a0 = fmaf(wx0, XV(s), bias0), a1 = 0.f;
                    DOT12G(R0v, g0, a0, a1);
                    cur0 = fmaxf(a0 + a1, 0.f);
                    dst[s * RSTR + jj] = (_Float16)cur0;   // unconditional (padded row)
                    GATHER(cur0, R0v);
                }
                if (pf) { xq0 = xn0; xq1 = xn1; xq2 = xn2; xq3 = xn3; }
            }
        } else {
            if (c >= 1) {
                const _Float16* src = pub + (size_t)(rp * NB + bl) * K * RSTR;
                int4v iA0 = ((const int4v*)src)[0];
                int4v iA1 = ((const int4v*)src)[1];
                int4v iA2 = ((const int4v*)src)[2];
                #pragma unroll
                for (int s = 0; s < K; ++s) {
                    int4v iB0, iB1, iB2;
                    if (s + 1 < K) {
                        const int4v* nr = (const int4v*)(src + (s + 1) * RSTR);
                        iB0 = nr[0]; iB1 = nr[1]; iB2 = nr[2];
                    }
                    // l1(t): inp = h0(t) row, own = R1v = h1(t-1)
                    float a0 = bias1, a1 = 0.f, a2 = 0.f, a3 = 0.f;
                    DOT12N(iA0, iA1, iA2, a0, a1);
                    DOT12G(R1v, g1h, a2, a3);
                    // l2(t-1): inp = R1v = h1(t-1), own = R2v = h2(t-2)
                    float b0 = bias2, b1 = 0.f, b2 = 0.f, b3 = 0.f;
                    DOT12G(R1v, g2i, b0, b1);
                    DOT12G(R2v, g2h, b2, b3);
                    const float v1 = fmaxf((a0 + a1) + (a2 + a3), 0.f);
                    const float v2 = fmaxf((b0 + b1) + (b2 + b3), 0.f);
                    const int t = (c - 1) * K + s;
                    cur1 = v1;
                    cur2 = (t >= 1) ? v2 : cur2;   // t=0 computes h2(-1): discard
                    GATHER(cur1, R1v);
                    GATHER(cur2, R2v);
                    if (s + 1 < K) { iA0 = iB0; iA1 = iB1; iA2 = iB2; }
                }
            }
        }
        __syncthreads();
    }

    // ---- wave1 epilogue: l2(T-1) from final gathers ----
    if (w == 1) {
        float b0 = bias2, b1 = 0.f, b2 = 0.f, b3 = 0.f;
        DOT12G(R1v, g2i, b0, b1);
        DOT12G(R2v, g2h, b2, b3);
        cur2 = fmaxf((b0 + b1) + (b2 + b3), 0.f);
    }
#undef XV
#undef DOT12N
#undef DOT12G
#undef GATHER

    // ---- h_final ----
    if (w == 0) {
        if (act) out[BATCH + (size_t)(0 * BATCH + bg) * HID + uL] = cur0;
    } else if (act) {
        out[BATCH + (size_t)(1 * BATCH + bg) * HID + uL] = cur1;
        out[BATCH + (size_t)(2 * BATCH + bg) * HID + uL] = cur2;
        h2f[bl][uL] = cur2;
    }
    __syncthreads();

    // ---- MLP head on h2(T-1) ----
    if (w == 1 && act) {
        const float4* w1r = (const float4*)(W1 + uL * HID);
        const float4* hv  = (const float4*)&h2f[bl][0];
        float a = b1[uL];
        a = dot4(w1r[0], hv[0], a); a = dot4(w1r[1], hv[1], a);
        a = dot4(w1r[2], hv[2], a); a = dot4(w1r[3], hv[3], a);
        a = dot4(w1r[4], hv[4], a); a = dot4(w1r[5], hv[5], a);
        mbuf[bl][uL] = fmaxf(a, 0.f);
    }
    __syncthreads();
    if (w == 1 && jj == 0) {
        float a = b2[0];
        #pragma unroll
        for (int k = 0; k < HID; ++k) a = fmaf(W2[k], mbuf[bl][k], a);
        out[bg] = fmaxf(a, 0.f);
    }
}

__global__ __launch_bounds__(TPB, 1) void rnn_2w_kernel(
    const float* __restrict__ x, const float* __restrict__ h_in,
    const float* __restrict__ Wih0, const float* __restrict__ bih0,
    const float* __restrict__ Whh0, const float* __restrict__ bhh0,
    const float* __restrict__ Wih1, const float* __restrict__ bih1,
    const float* __restrict__ Whh1, const float* __restrict__ bhh1,
    const float* __restrict__ Wih2, const float* __restrict__ bih2,
    const float* __restrict__ Whh2, const float* __restrict__ bhh2,
    const float* __restrict__ W1,   const float* __restrict__ b1,
    const float* __restrict__ W2,   const float* __restrict__ b2,
    float* __restrict__ out)
{
    __shared__ __align__(16) _Float16 pub[2 * NB * K * RSTR];
    __shared__ float h2f[NB][HID];
    __shared__ float mbuf[NB][HID];

    const int lane = threadIdx.x & 63;
    const int d0 = __builtin_amdgcn_readfirstlane(rr<2>(lane));
    const int dir = (d0 == 2) ? 1 : -1;

#if __has_builtin(__builtin_amdgcn_permlane16_swap)
    uint2v sw = __builtin_amdgcn_permlane16_swap((unsigned)lane, (unsigned)lane,
                                                 false, false);
    const int s0  = __builtin_amdgcn_readlane((int)sw.x, 0);
    const int s16 = __builtin_amdgcn_readlane((int)sw.x, 16);
    const bool ok   = (s0 == 0 && s16 == 0) || (s0 == 16 && s16 == 16);
    const bool flip = (s0 == 16);
    if (ok) {
        run_rnn<false>(x, h_in, Wih0, bih0, Whh0, bhh0, Wih1, bih1, Whh1, bhh1,
                       Wih2, bih2, Whh2, bhh2, W1, b1, W2, b2, out,
                       dir, flip, pub, h2f, mbuf);
    } else {
        run_rnn<true>(x, h_in, Wih0, bih0, Whh0, bhh0, Wih1, bih1, Whh1, bhh1,
                      Wih2, bih2, Whh2, bhh2, W1, b1, W2, b2, out,
                      dir, false, pub, h2f, mbuf);
    }
#else
    run_rnn<true>(x, h_in, Wih0, bih0, Whh0, bhh0, Wih1, bih1, Whh1, bhh1,
                  Wih2, bih2, Whh2, bhh2, W1, b1, W2, b2, out,
                  dir, false, pub, h2f, mbuf);
#endif
}

extern "C" void kernel_launch(void* const* d_in, const int* in_sizes, int n_in,
                              void* d_out, int out_size, void* d_ws, size_t ws_size,
                              hipStream_t stream) {
    const float* x    = (const float*)d_in[0];
    const float* h_in = (const float*)d_in[1];
    const float* Wih0 = (const float*)d_in[2];
    const float* bih0 = (const float*)d_in[3];
    const float* Whh0 = (const float*)d_in[4];
    const float* bhh0 = (const float*)d_in[5];
    const float* Wih1 = (const float*)d_in[6];
    const float* bih1 = (const float*)d_in[7];
    const float* Whh1 = (const float*)d_in[8];
    const float* bhh1 = (const float*)d_in[9];
    const float* Wih2 = (const float*)d_in[10];
    const float* bih2 = (const float*)d_in[11];
    const float* Whh2 = (const float*)d_in[12];
    const float* bhh2 = (const float*)d_in[13];
    const float* W1   = (const float*)d_in[14];
    const float* b1   = (const float*)d_in[15];
    const float* W2   = (const float*)d_in[16];
    const float* b2   = (const float*)d_in[17];
    float* out = (float*)d_out;

    dim3 grid(BATCH / NB);   // 512 blocks -> 2 blocks/CU, 4 waves/CU (~1/SIMD)
    dim3 block(TPB);         // wave0 = l0, wave1 = l1+l2
    hipLaunchKernelGGL(rnn_2w_kernel, grid, block, 0, stream,
                       x, h_in, Wih0, bih0, Whh0, bhh0,
                       Wih1, bih1, Whh1, bhh1, Wih2, bih2, Whh2, bhh2,
                       W1, b1, W2, b2, out);
}

// Round 15
// 510.372 us; speedup vs baseline: 2.4744x; 2.4744x over previous
//
#include <hip/hip_runtime.h>

#define HID   24
#define T_LEN 4096
#define BATCH 1024
#define NB    2                  // batches per block (one per 32-lane half)
#define K     32                 // timesteps per chunk (pipeline skew per layer)
#define NC    (T_LEN / K)        // 128 active chunks per layer
#define CTOT  (NC + 2)           // 130 ticks (3-layer skew)
#define TPB   192                // 3 waves: wave w == layer w
#define PS    32                 // padded row stride (elements)

typedef __attribute__((ext_vector_type(2))) _Float16 h2v;
typedef __attribute__((ext_vector_type(4))) int      int4v;

#if __has_builtin(__builtin_amdgcn_fdot2)
__device__ __forceinline__ float dot2f(int p, int w, float acc) {
    return __builtin_amdgcn_fdot2(__builtin_bit_cast(h2v, p),
                                  __builtin_bit_cast(h2v, w), acc, false);
}
#else
__device__ __forceinline__ float dot2f(int p, int w, float acc) {
    h2v a = __builtin_bit_cast(h2v, p), b = __builtin_bit_cast(h2v, w);
    acc = fmaf((float)a.x, (float)b.x, acc);
    return fmaf((float)a.y, (float)b.y, acc);
}
#endif

__device__ __forceinline__ float dot4(const float4 a, const float4 b, float acc) {
    acc = fmaf(a.x, b.x, acc);
    acc = fmaf(a.y, b.y, acc);
    acc = fmaf(a.z, b.z, acc);
    return fmaf(a.w, b.w, acc);
}

// pack two f32 -> packed f16 pair dword
#define PKF(A_, B_)                                                                 \
    (((int)__builtin_bit_cast(unsigned short, (_Float16)(B_)) << 16) |              \
     (int)__builtin_bit_cast(unsigned short, (_Float16)(A_)))

__global__ __launch_bounds__(TPB, 1) void rnn_bal_kernel(
    const float* __restrict__ x,     // [B, T]
    const float* __restrict__ h_in,  // [3, B, 24]
    const float* __restrict__ Wih0, const float* __restrict__ bih0,
    const float* __restrict__ Whh0, const float* __restrict__ bhh0,
    const float* __restrict__ Wih1, const float* __restrict__ bih1,
    const float* __restrict__ Whh1, const float* __restrict__ bhh1,
    const float* __restrict__ Wih2, const float* __restrict__ bih2,
    const float* __restrict__ Whh2, const float* __restrict__ bhh2,
    const float* __restrict__ W1,   const float* __restrict__ b1,
    const float* __restrict__ W2,   const float* __restrict__ b2,
    float* __restrict__ out)         // [1024 (y)] ++ [3*1024*24 (h_final)]
{
    // l0 own row: per-step ping-pong (only l0 touches it)
    __shared__ __align__(16) _Float16 row0[2][NB][PS];
    // l2 own row: per-step ping-pong
    __shared__ __align__(16) _Float16 row2[2][NB][PS];
    // h1 publication rows (producer l1 own-read + consumer l2), tick parity
    __shared__ __align__(16) _Float16 pub1[2][NB][K][PS];
    // l1 input partials (Wih1 . h0(t)), f32, tick parity
    __shared__ __align__(16) float part1[2][NB][K][PS];
    __shared__ float h2f[NB][HID];
    __shared__ float mbuf[NB][HID];

    const int tid  = threadIdx.x;
    const int l    = tid >> 6;        // wave == layer
    const int lane = tid & 63;
    const int bl   = lane >> 5;       // batch half
    const int jj   = lane & 31;
    const bool act = (jj < HID);
    const int uL   = act ? jj : (jj - 8);   // pad lanes duplicate units 16-23
    const int bg   = blockIdx.x * NB + bl;

    // ---- packed-f16 weights in named int4v registers (natural pair order) ----
    int4v whA, whB, whC;              // own-h row for this wave's layer
    int4v wiA = {0,0,0,0}, wiB = {0,0,0,0}, wiC = {0,0,0,0};
    // l0: wi* = Wih1 row (for the partial);  l2: wi* = Wih2 row;  l1: unused
    float wx0 = 0.f, bias;

#define MK3(ROW, DA, DB, DC) do {                                                   \
        DA = (int4v){PKF((ROW)[0], (ROW)[1]),   PKF((ROW)[2], (ROW)[3]),            \
                     PKF((ROW)[4], (ROW)[5]),   PKF((ROW)[6], (ROW)[7])};           \
        DB = (int4v){PKF((ROW)[8], (ROW)[9]),   PKF((ROW)[10], (ROW)[11]),          \
                     PKF((ROW)[12], (ROW)[13]), PKF((ROW)[14], (ROW)[15])};         \
        DC = (int4v){PKF((ROW)[16], (ROW)[17]), PKF((ROW)[18], (ROW)[19]),          \
                     PKF((ROW)[20], (ROW)[21]), PKF((ROW)[22], (ROW)[23])};         \
    } while (0)

    if (l == 0) {
        MK3(Whh0 + uL * HID, whA, whB, whC);
        MK3(Wih1 + uL * HID, wiA, wiB, wiC);   // partial weights (output unit uL)
        wx0  = Wih0[uL];
        bias = bih0[uL] + bhh0[uL];
    } else if (l == 1) {
        MK3(Whh1 + uL * HID, whA, whB, whC);
        bias = bih1[uL] + bhh1[uL];
    } else {
        MK3(Whh2 + uL * HID, whA, whB, whC);
        MK3(Wih2 + uL * HID, wiA, wiB, wiC);
        bias = bih2[uL] + bhh2[uL];
    }
#undef MK3

    float cur = h_in[(l * BATCH + bg) * HID + uL];

    // seed: l0 own row (read at s=0 -> row0[1]); l1 row(-1) in pub1[0][bl][K-1];
    // l2 own row (read at s=0 -> row2[1])
    if (l == 0) row0[1][bl][jj] = (_Float16)cur;
    if (l == 1) pub1[0][bl][K - 1][jj] = (_Float16)cur;
    if (l == 2) row2[1][bl][jj] = (_Float16)cur;

    // ---- x quads in registers (l0): 8 current + 8 prefetch ----
    const float* xrow = x + (size_t)bg * T_LEN;
    float4 xq[8], xn[8];
    if (l == 0) {
        const float4* xr = (const float4*)xrow;
        #pragma unroll
        for (int q = 0; q < 8; ++q) xq[q] = xr[q];
    }
#define XV(S)                                                                       \
    (((S) & 3) == 0 ? xq[(S) >> 2].x : ((S) & 3) == 1 ? xq[(S) >> 2].y              \
   : ((S) & 3) == 2 ? xq[(S) >> 2].z : xq[(S) >> 2].w)

// 12 packed dots of row triple (V0,V1,V2) vs weight triple into a0,a1
#define DOT12(V0_, V1_, V2_, W0_, W1_, W2_, A0_, A1_)                               \
    A0_ = dot2f(V0_.x, W0_.x, A0_); A1_ = dot2f(V0_.y, W0_.y, A1_);                 \
    A0_ = dot2f(V0_.z, W0_.z, A0_); A1_ = dot2f(V0_.w, W0_.w, A1_);                 \
    A0_ = dot2f(V1_.x, W1_.x, A0_); A1_ = dot2f(V1_.y, W1_.y, A1_);                 \
    A0_ = dot2f(V1_.z, W1_.z, A0_); A1_ = dot2f(V1_.w, W1_.w, A1_);                 \
    A0_ = dot2f(V2_.x, W2_.x, A0_); A1_ = dot2f(V2_.y, W2_.y, A1_);                 \
    A0_ = dot2f(V2_.z, W2_.z, A0_); A1_ = dot2f(V2_.w, W2_.w, A1_);

    __syncthreads();

    // ---- chunked, layer-skewed scan: tick c; l0->chunk c, l1->c-1, l2->c-2 ----
    for (int c = 0; c < CTOT; ++c) {
        const int wp = c & 1, rp = wp ^ 1;
        if (l == 0) {
            if (c < NC) {
                const bool pf = (c + 1 < NC);
                if (pf) {
                    const float4* xr = (const float4*)(xrow + (size_t)(c + 1) * K);
                    #pragma unroll
                    for (int q = 0; q < 8; ++q) xn[q] = xr[q];
                }
                #pragma unroll
                for (int s = 0; s < K; ++s) {
                    const int4v* own = (const int4v*)&row0[(s + 1) & 1][bl][0];
                    const int4v o0 = own[0], o1 = own[1], o2 = own[2]; // h0(t-1)
                    // own-h dot -> h0(t)
                    float a0 = fmaf(wx0, XV(s), bias), a1 = 0.f;
                    DOT12(o0, o1, o2, whA, whB, whC, a0, a1);
                    cur = fmaxf(a0 + a1, 0.f);
                    row0[s & 1][bl][jj] = (_Float16)cur;
                    // l1's input partial for step t-1 (off-chain)
                    if (s > 0) {
                        float p0 = 0.f, p1 = 0.f;
                        DOT12(o0, o1, o2, wiA, wiB, wiC, p0, p1);
                        part1[wp][bl][s - 1][jj] = p0 + p1;
                    }
                }
                // epilogue: partial for the chunk's last step (one RAW per chunk)
                {
                    const int4v* own = (const int4v*)&row0[1][bl][0];  // row(K-1)
                    const int4v o0 = own[0], o1 = own[1], o2 = own[2];
                    float p0 = 0.f, p1 = 0.f;
                    DOT12(o0, o1, o2, wiA, wiB, wiC, p0, p1);
                    part1[wp][bl][K - 1][jj] = p0 + p1;
                }
                if (pf) {
                    #pragma unroll
                    for (int q = 0; q < 8; ++q) xq[q] = xn[q];
                }
            }
        } else if (l == 1) {
            if (c >= 1 && c < 1 + NC) {
                #pragma unroll
                for (int s = 0; s < K; ++s) {
                    const int4v* own = (s == 0)
                        ? (const int4v*)&pub1[rp][bl][K - 1][0]
                        : (const int4v*)&pub1[wp][bl][s - 1][0];
                    const int4v o0 = own[0], o1 = own[1], o2 = own[2]; // h1(t-1)
                    const float pin = part1[rp][bl][s][jj];            // Wih1.h0(t)
                    float a0 = pin + bias, a1 = 0.f;
                    DOT12(o0, o1, o2, whA, whB, whC, a0, a1);
                    cur = fmaxf(a0 + a1, 0.f);
                    pub1[wp][bl][s][jj] = (_Float16)cur;
                }
            }
        } else {
            if (c >= 2 && c < 2 + NC) {
                const int4v* src = (const int4v*)&pub1[rp][bl][0][0];
                int4v iA0 = src[0], iA1 = src[1], iA2 = src[2];
                #pragma unroll
                for (int s = 0; s < K; ++s) {
                    int4v iB0, iB1, iB2;
                    if (s + 1 < K) {
                        const int4v* nr = (const int4v*)&pub1[rp][bl][s + 1][0];
                        iB0 = nr[0]; iB1 = nr[1]; iB2 = nr[2];
                    }
                    const int4v* own = (const int4v*)&row2[(s + 1) & 1][bl][0];
                    const int4v o0 = own[0], o1 = own[1], o2 = own[2]; // h2(t-1)
                    float a0 = bias, a1 = 0.f, a2 = 0.f, a3 = 0.f;
                    DOT12(iA0, iA1, iA2, wiA, wiB, wiC, a0, a1);       // Wih2.h1(t)
                    DOT12(o0, o1, o2, whA, whB, whC, a2, a3);
                    cur = fmaxf((a0 + a1) + (a2 + a3), 0.f);
                    row2[s & 1][bl][jj] = (_Float16)cur;
                    if (s + 1 < K) { iA0 = iB0; iA1 = iB1; iA2 = iB2; }
                }
            }
        }
        __syncthreads();
    }
#undef XV
#undef DOT12

    // ---- h_final from f32 running values ----
    if (act) out[BATCH + (size_t)(l * BATCH + bg) * HID + uL] = cur;

    // ---- MLP head on h2(T-1) ----
    if (l == 2 && act) h2f[bl][uL] = cur;
    __syncthreads();
    if (l == 2 && act) {
        const float4* w1r = (const float4*)(W1 + uL * HID);
        const float4* hv  = (const float4*)&h2f[bl][0];
        float a = b1[uL];
        a = dot4(w1r[0], hv[0], a); a = dot4(w1r[1], hv[1], a);
        a = dot4(w1r[2], hv[2], a); a = dot4(w1r[3], hv[3], a);
        a = dot4(w1r[4], hv[4], a); a = dot4(w1r[5], hv[5], a);
        mbuf[bl][uL] = fmaxf(a, 0.f);
    }
    __syncthreads();
    if (l == 2 && jj == 0) {
        float a = b2[0];
        #pragma unroll
        for (int k = 0; k < HID; ++k) a = fmaf(W2[k], mbuf[bl][k], a);
        out[bg] = fmaxf(a, 0.f);
    }
}

extern "C" void kernel_launch(void* const* d_in, const int* in_sizes, int n_in,
                              void* d_out, int out_size, void* d_ws, size_t ws_size,
                              hipStream_t stream) {
    const float* x    = (const float*)d_in[0];
    const float* h_in = (const float*)d_in[1];
    const float* Wih0 = (const float*)d_in[2];
    const float* bih0 = (const float*)d_in[3];
    const float* Whh0 = (const float*)d_in[4];
    const float* bhh0 = (const float*)d_in[5];
    const float* Wih1 = (const float*)d_in[6];
    const float* bih1 = (const float*)d_in[7];
    const float* Whh1 = (const float*)d_in[8];
    const float* bhh1 = (const float*)d_in[9];
    const float* Wih2 = (const float*)d_in[10];
    const float* bih2 = (const float*)d_in[11];
    const float* Whh2 = (const float*)d_in[12];
    const float* bhh2 = (const float*)d_in[13];
    const float* W1   = (const float*)d_in[14];
    const float* b1   = (const float*)d_in[15];
    const float* W2   = (const float*)d_in[16];
    const float* b2   = (const float*)d_in[17];
    float* out = (float*)d_out;

    dim3 grid(BATCH / NB);   // 512 blocks -> 2 blocks/CU, 6 waves/CU
    dim3 block(TPB);         // 3 waves (wave == layer)
    hipLaunchKernelGGL(rnn_bal_kernel, grid, block, 0, stream,
                       x, h_in, Wih0, bih0, Whh0, bhh0,
                       Wih1, bih1, Whh1, bhh1, Wih2, bih2, Whh2, bhh2,
                       W1, b1, W2, b2, out);
}